// Round 1
// baseline (255.530 us; speedup 1.0000x reference)
//
#include <hip/hip_runtime.h>
#include <hip/hip_bf16.h>

// Problem constants
#define BB 128
#define NN 36
#define DD 1024
#define HH 16
#define DG 64
#define PEC 64
#define ROWS (BB*NN)          // 4608
#define NCOLS (3*DD)          // 3072: [q | k | vw]

typedef __attribute__((ext_vector_type(8))) __bf16 bf16x8;
typedef __attribute__((ext_vector_type(4))) float f32x4;

// ---------------- fp32 -> bf16 convert ----------------
__global__ __launch_bounds__(256) void cvt_bf16_kernel(const float* __restrict__ src,
                                                       unsigned short* __restrict__ dst, int n) {
    int i = blockIdx.x * 256 + threadIdx.x;
    if (i < n) {
        __hip_bfloat16 h = __float2bfloat16(src[i]);
        dst[i] = *reinterpret_cast<unsigned short*>(&h);
    }
}

// ---------------- bias concat: [bq | bk | 0] ----------------
__global__ __launch_bounds__(256) void build_bcat_kernel(const float* __restrict__ bq,
                                                         const float* __restrict__ bk,
                                                         float* __restrict__ bcat) {
    int i = blockIdx.x * 256 + threadIdx.x;
    if (i < NCOLS)
        bcat[i] = (i < DD) ? bq[i] : ((i < 2*DD) ? bk[i - DD] : 0.f);
}

// ---------------- GEMM: P(4608x3072) = roi_bf(4608x1024) @ Wcat_bf(3072x1024)^T + bcat ---------
// 128x128 tile, BK=32, 4 waves each computing 64x64 via 4x4 MFMA 16x16x32 bf16.
__global__ __launch_bounds__(256) void gemm_kernel(const unsigned short* __restrict__ A,
                                                   const unsigned short* __restrict__ Bm,
                                                   const float* __restrict__ bcat,
                                                   float* __restrict__ P) {
    __shared__ __align__(16) unsigned short As[128 * 32];
    __shared__ __align__(16) unsigned short Bs[128 * 32];
    const int tid  = threadIdx.x;
    const int m0   = (blockIdx.x % 36) * 128;
    const int n0   = (blockIdx.x / 36) * 128;
    const int wave = tid >> 6, lane = tid & 63;
    const int quad = lane >> 4, l16 = lane & 15;
    const int wm = (wave & 1) * 64, wn = (wave >> 1) * 64;

    f32x4 acc[4][4] = {};

    for (int k0 = 0; k0 < DD; k0 += 32) {
        // stage A,B tiles (each 128x32 bf16 = 4096 elems; 256 thr * 8 elems * 2 passes)
#pragma unroll
        for (int p = 0; p < 2; p++) {
            int L = (p * 256 + tid) * 8;
            int row = L >> 5, col = L & 31;
            *(bf16x8*)&As[L] = *(const bf16x8*)&A[(size_t)(m0 + row) * DD + k0 + col];
            *(bf16x8*)&Bs[L] = *(const bf16x8*)&Bm[(size_t)(n0 + row) * DD + k0 + col];
        }
        __syncthreads();

        bf16x8 af[4], bf[4];
#pragma unroll
        for (int mi = 0; mi < 4; mi++)
            af[mi] = *(const bf16x8*)&As[(wm + mi * 16 + l16) * 32 + quad * 8];
#pragma unroll
        for (int ni = 0; ni < 4; ni++)
            bf[ni] = *(const bf16x8*)&Bs[(wn + ni * 16 + l16) * 32 + quad * 8];
#pragma unroll
        for (int mi = 0; mi < 4; mi++)
#pragma unroll
            for (int ni = 0; ni < 4; ni++)
                acc[mi][ni] = __builtin_amdgcn_mfma_f32_16x16x32_bf16(af[mi], bf[ni], acc[mi][ni], 0, 0, 0);
        __syncthreads();
    }

    // epilogue: C/D layout col=lane&15, row=quad*4+r
#pragma unroll
    for (int mi = 0; mi < 4; mi++)
#pragma unroll
        for (int ni = 0; ni < 4; ni++) {
            int row = m0 + wm + mi * 16 + quad * 4;
            int col = n0 + wn + ni * 16 + l16;
            float bc = bcat[col];
#pragma unroll
            for (int r = 0; r < 4; r++)
                P[(size_t)(row + r) * NCOLS + col] = acc[mi][ni][r] + bc;
        }
}

// ---------------- pos: pos_log[b,h,n,m] = log(max(relu(pe[b,n,m,:].Wpos[h,:]+bpos[h]),1e-6)) ----
#define AP 68   // padded leading dim (mult of 4 for aligned float4)
__global__ __launch_bounds__(256) void pos_kernel(const float* __restrict__ pe,
                                                  const float* __restrict__ Wpos,
                                                  const float* __restrict__ bpos,
                                                  float* __restrict__ pos_log) {
    __shared__ __align__(16) float pes[NN * AP];
    __shared__ __align__(16) float wps[HH * AP];
    __shared__ float bps[HH];
    const int row = blockIdx.x;            // b*36 + n
    const int b = row / NN, n = row - b * NN;
    const int tid = threadIdx.x;

    for (int i = tid; i < NN * 64; i += 256)
        pes[(i >> 6) * AP + (i & 63)] = pe[((size_t)row * NN + (i >> 6)) * 64 + (i & 63)];
    for (int i = tid; i < HH * 64; i += 256)
        wps[(i >> 6) * AP + (i & 63)] = Wpos[i];
    if (tid < HH) bps[tid] = bpos[tid];
    __syncthreads();

    for (int i = tid; i < HH * NN; i += 256) {
        int h = i / NN, m = i - h * NN;
        f32x4 a4 = {0.f, 0.f, 0.f, 0.f};
#pragma unroll
        for (int e = 0; e < 64; e += 4) {
            f32x4 pv = *(const f32x4*)&pes[m * AP + e];
            f32x4 wv = *(const f32x4*)&wps[h * AP + e];
            a4 += pv * wv;
        }
        float d = a4[0] + a4[1] + a4[2] + a4[3] + bps[h];
        d = fmaxf(d, 0.f);
        d = __logf(fmaxf(d, 1e-6f));
        pos_log[(((size_t)b * HH + h) * NN + n) * NN + m] = d;
    }
}

// ---------------- fused attention per (b,h) ----------------
__global__ __launch_bounds__(256) void attn_kernel(const float* __restrict__ P,
                                                   const float* __restrict__ pos_log,
                                                   const int* __restrict__ adj,
                                                   const float* __restrict__ lbl,
                                                   const float* __restrict__ bout,
                                                   float* __restrict__ out) {
    const int b = blockIdx.x >> 4;
    const int h = blockIdx.x & 15;
    __shared__ __align__(16) float qs[NN * AP];
    __shared__ __align__(16) float ks[NN * AP];
    __shared__ __align__(16) float vws[NN * AP];
    __shared__ float affs[NN * 40];
    const int tid = threadIdx.x;

    // load q,k,vw tiles (36x64 each)
    for (int i = tid; i < NN * 64; i += 256) {
        int n = i >> 6, e = i & 63;
        size_t base = (size_t)(b * NN + n) * NCOLS;
        qs [n * AP + e] = P[base + h * 64 + e];
        ks [n * AP + e] = P[base + DD + h * 64 + e];
        vws[n * AP + e] = P[base + 2 * DD + h * 64 + e];
    }
    __syncthreads();

    // aff + log(pos) + mask + bias
    const float scale = 0.125f;   // 1/sqrt(64)
    for (int i = tid; i < NN * NN; i += 256) {
        int n = i / NN, m = i - n * NN;
        f32x4 a4 = {0.f, 0.f, 0.f, 0.f};
#pragma unroll
        for (int e = 0; e < 64; e += 4) {
            f32x4 qv = *(const f32x4*)&qs[n * AP + e];
            f32x4 kv = *(const f32x4*)&ks[m * AP + e];
            a4 += qv * kv;
        }
        float w = (a4[0] + a4[1] + a4[2] + a4[3]) * scale;
        w += pos_log[(((size_t)b * HH + h) * NN + n) * NN + m];
        int amask = adj[(size_t)(b * NN + n) * NN + m];
        if (amask <= 0) w = -9e15f;
        w += lbl[(size_t)(b * NN + n) * NN + m];
        affs[n * 40 + m] = w;
    }
    __syncthreads();

    // softmax over m (wave-parallel; lane=m)
    const int wave = tid >> 6, lane = tid & 63;
    for (int n = wave; n < NN; n += 4) {
        float v = (lane < NN) ? affs[n * 40 + lane] : -3.4e38f;
        float mx = v;
#pragma unroll
        for (int off = 32; off; off >>= 1) mx = fmaxf(mx, __shfl_xor(mx, off));
        float e = (lane < NN) ? __expf(v - mx) : 0.f;
        float s = e;
#pragma unroll
        for (int off = 32; off; off >>= 1) s += __shfl_xor(s, off);
        if (lane < NN) affs[n * 40 + lane] = e / s;
    }
    __syncthreads();

    // out[n][e0..e0+3] = sum_m att[n][m] * vw[m][e]
    for (int i = tid; i < NN * 16; i += 256) {
        int n = i >> 4, e0 = (i & 15) * 4;
        f32x4 acc = {0.f, 0.f, 0.f, 0.f};
        for (int m = 0; m < NN; m++) {
            float a = affs[n * 40 + m];
            f32x4 vv = *(const f32x4*)&vws[m * AP + e0];
            acc += a * vv;
        }
        f32x4 bo = *(const f32x4*)&bout[h * 64 + e0];
        *(f32x4*)&out[(size_t)(b * NN + n) * DD + h * 64 + e0] = acc + bo;
    }
}

// ---------------- launcher ----------------
extern "C" void kernel_launch(void* const* d_in, const int* in_sizes, int n_in,
                              void* d_out, int out_size, void* d_ws, size_t ws_size,
                              hipStream_t stream) {
    const float* roi  = (const float*)d_in[0];
    const int*   adj  = (const int*)  d_in[1];
    const float* pe   = (const float*)d_in[2];
    const float* lbl  = (const float*)d_in[3];
    const float* Wq   = (const float*)d_in[4];
    const float* bq   = (const float*)d_in[5];
    const float* Wk   = (const float*)d_in[6];
    const float* bk   = (const float*)d_in[7];
    const float* Wpos = (const float*)d_in[8];
    const float* bpos = (const float*)d_in[9];
    const float* Wout = (const float*)d_in[10];
    const float* bout = (const float*)d_in[11];
    float* out = (float*)d_out;

    char* w = (char*)d_ws;
    unsigned short* roi_bf  = (unsigned short*)(w);                 // 4718592 bf16
    unsigned short* Wcat_bf = (unsigned short*)(w + 9437184);       // 3145728 bf16
    float*          bcat    = (float*)(w + 15728640);               // 3072 f32
    float*          P       = (float*)(w + 15740928);               // 4608*3072 f32
    float*          pos_log = (float*)(w + 72364032);               // 128*16*36*36 f32

    // bf16 conversions
    cvt_bf16_kernel<<<(ROWS * DD + 255) / 256, 256, 0, stream>>>(roi, roi_bf, ROWS * DD);
    cvt_bf16_kernel<<<(DD * DD + 255) / 256, 256, 0, stream>>>(Wq,   Wcat_bf,            DD * DD);
    cvt_bf16_kernel<<<(DD * DD + 255) / 256, 256, 0, stream>>>(Wk,   Wcat_bf + DD * DD,  DD * DD);
    cvt_bf16_kernel<<<(DD * DD + 255) / 256, 256, 0, stream>>>(Wout, Wcat_bf + 2*DD*DD,  DD * DD);
    build_bcat_kernel<<<(NCOLS + 255) / 256, 256, 0, stream>>>(bq, bk, bcat);

    // big GEMM: q,k,vw
    gemm_kernel<<<36 * 24, 256, 0, stream>>>(roi_bf, Wcat_bf, bcat, P);

    // positional logits
    pos_kernel<<<ROWS, 256, 0, stream>>>(pe, Wpos, bpos, pos_log);

    // fused attention
    attn_kernel<<<BB * HH, 256, 0, stream>>>(P, pos_log, adj, lbl, bout, out);
}

// Round 2
// 217.321 us; speedup vs baseline: 1.1758x; 1.1758x over previous
//
#include <hip/hip_runtime.h>
#include <hip/hip_bf16.h>

#define BB 128
#define NN 36
#define DD 1024
#define HH 16
#define ROWS (BB*NN)          // 4608
#define NCOLS (3*DD)          // 3072: [q | k | vw]

typedef __attribute__((ext_vector_type(8))) __bf16 bf16x8;
typedef __attribute__((ext_vector_type(4))) float f32x4;
typedef __attribute__((ext_vector_type(4))) unsigned short us4;

__device__ inline unsigned short f2bf(float f) {
    __hip_bfloat16 h = __float2bfloat16(f);
    return *reinterpret_cast<unsigned short*>(&h);
}

__device__ inline void async16(const unsigned short* g, unsigned short* l) {
    __builtin_amdgcn_global_load_lds((const __attribute__((address_space(1))) unsigned int*)g,
                                     (__attribute__((address_space(3))) unsigned int*)l, 16, 0, 0);
}

// ---------------- fp32 -> bf16 convert, float4-vectorized ----------------
__global__ __launch_bounds__(256) void cvt4_kernel(const float* __restrict__ src,
                                                   unsigned short* __restrict__ dst, int n4) {
    int i = blockIdx.x * 256 + threadIdx.x;
    if (i < n4) {
        f32x4 v = ((const f32x4*)src)[i];
        us4 o;
        o.x = f2bf(v[0]); o.y = f2bf(v[1]); o.z = f2bf(v[2]); o.w = f2bf(v[3]);
        ((us4*)dst)[i] = o;
    }
}

// ---------------- GEMM: P(4608x3072 bf16) = roi_bf @ Wcat_bf^T + [bq|bk|0] ----------------
// m97 structure: 128x128 tile, BK=32, global_load_lds width=16, 4 waves x (4x4 MFMA 16x16x32).
__global__ __launch_bounds__(256) void gemm_kernel(const unsigned short* __restrict__ A,
                                                   const unsigned short* __restrict__ Bm,
                                                   const float* __restrict__ bq,
                                                   const float* __restrict__ bk,
                                                   unsigned short* __restrict__ P) {
    __shared__ __align__(16) unsigned short As[128 * 32];
    __shared__ __align__(16) unsigned short Bs[128 * 32];
    const int tid  = threadIdx.x;
    const int m0   = (blockIdx.x % 36) * 128;
    const int n0   = (blockIdx.x / 36) * 128;
    const int wave = tid >> 6, lane = tid & 63;
    const int quad = lane >> 4, l16 = lane & 15;
    const int wm = (wave & 1) * 64, wn = (wave >> 1) * 64;

    // staging chunks: 512 chunks of 8 bf16 per 128x32 tile; wave w instr p covers chunks [w*128+p*64, +64)
    const int c0 = wave * 128 + lane;
    const int r0 = c0 >> 2, kc0 = (c0 & 3) * 8;
    const int c1 = c0 + 64;
    const int r1 = c1 >> 2, kc1 = (c1 & 3) * 8;
    unsigned short* lA = As + wave * 1024;   // chunk base * 8 elems
    unsigned short* lB = Bs + wave * 1024;

    f32x4 acc[4][4] = {};

    for (int k0 = 0; k0 < DD; k0 += 32) {
        async16(A  + (size_t)(m0 + r0) * DD + k0 + kc0, lA);
        async16(A  + (size_t)(m0 + r1) * DD + k0 + kc1, lA + 512);
        async16(Bm + (size_t)(n0 + r0) * DD + k0 + kc0, lB);
        async16(Bm + (size_t)(n0 + r1) * DD + k0 + kc1, lB + 512);
        __syncthreads();

        bf16x8 af[4], bf[4];
#pragma unroll
        for (int mi = 0; mi < 4; mi++)
            af[mi] = *(const bf16x8*)&As[(wm + mi * 16 + l16) * 32 + quad * 8];
#pragma unroll
        for (int ni = 0; ni < 4; ni++)
            bf[ni] = *(const bf16x8*)&Bs[(wn + ni * 16 + l16) * 32 + quad * 8];
#pragma unroll
        for (int mi = 0; mi < 4; mi++)
#pragma unroll
            for (int ni = 0; ni < 4; ni++)
                acc[mi][ni] = __builtin_amdgcn_mfma_f32_16x16x32_bf16(af[mi], bf[ni], acc[mi][ni], 0, 0, 0);
        __syncthreads();
    }

#pragma unroll
    for (int mi = 0; mi < 4; mi++)
#pragma unroll
        for (int ni = 0; ni < 4; ni++) {
            int row = m0 + wm + mi * 16 + quad * 4;
            int col = n0 + wn + ni * 16 + l16;
            float bc = (col < DD) ? bq[col] : ((col < 2 * DD) ? bk[col - DD] : 0.f);
#pragma unroll
            for (int r = 0; r < 4; r++)
                P[(size_t)(row + r) * NCOLS + col] = f2bf(acc[mi][ni][r] + bc);
        }
}

// ---------------- extra[b,h,n,m] = log(max(relu(pe.Wpos[h]+bpos[h]),1e-6)) + mask + lbl ------
__global__ __launch_bounds__(256) void extra_kernel(const float* __restrict__ pe,
                                                    const float* __restrict__ Wpos,
                                                    const float* __restrict__ bpos,
                                                    const int* __restrict__ adj,
                                                    const float* __restrict__ lbl,
                                                    float* __restrict__ extra) {
    int idx = blockIdx.x * 256 + threadIdx.x;     // one (b,n,m) row; grid exactly 165888 threads
    f32x4 pr[16];
    const f32x4* pv = (const f32x4*)(pe + (size_t)idx * 64);
#pragma unroll
    for (int j = 0; j < 16; j++) pr[j] = pv[j];
    int a = adj[idx];
    float add = lbl[idx] + (a > 0 ? 0.f : -9e15f);
    int b = idx / 1296, nm = idx % 1296;
    size_t obase = (size_t)b * (16 * 1296) + nm % 36 + (size_t)(nm / 36) * 36;
    for (int hh = 0; hh < 16; hh++) {
        const f32x4* wv = (const f32x4*)(Wpos + hh * 64);
        f32x4 acc4 = {0.f, 0.f, 0.f, 0.f};
#pragma unroll
        for (int j = 0; j < 16; j++) acc4 += pr[j] * wv[j];
        float d = acc4[0] + acc4[1] + acc4[2] + acc4[3] + bpos[hh];
        d = fmaxf(d, 0.f);
        d = __logf(fmaxf(d, 1e-6f));
        extra[obase + (size_t)hh * 1296] = d + add;
    }
}

// ---------------- fused MFMA attention: one wave per (b,h) ----------------
__global__ __launch_bounds__(64) void attn_kernel(const unsigned short* __restrict__ P,
                                                  const float* __restrict__ extra,
                                                  const float* __restrict__ bout,
                                                  float* __restrict__ out) {
    const int b = blockIdx.x >> 4;
    const int h = blockIdx.x & 15;
    __shared__ __align__(16) unsigned short vwT[64 * 64];   // [e][m], m in [36,64) zeroed
    __shared__ __align__(16) unsigned short atts[48 * 64];  // [n][m] bf16 att, m in [48,64) zeroed
    const int lane = threadIdx.x;
    const int quad = lane >> 4, l16 = lane & 15;
    const size_t pbase = (size_t)b * NN * NCOLS;

    // zero pads
    for (int i = lane; i < 64 * 28; i += 64) vwT[(i / 28) * 64 + 36 + (i % 28)] = 0;
    for (int i = lane; i < 48 * 16; i += 64) atts[(i >> 4) * 64 + 48 + (i & 15)] = 0;

    // stage vw^T: vwT[e][m] = P[b*36+m][2048 + h*64 + e]
    for (int i = lane; i < 576; i += 64) {
        int m = i >> 4, e0 = (i & 15) * 4;
        us4 v = *(const us4*)&P[pbase + (size_t)m * NCOLS + 2 * DD + h * 64 + e0];
        vwT[(e0 + 0) * 64 + m] = v.x;
        vwT[(e0 + 1) * 64 + m] = v.y;
        vwT[(e0 + 2) * 64 + m] = v.z;
        vwT[(e0 + 3) * 64 + m] = v.w;
    }

    // QK^T with fragments loaded straight from global (A-frag pattern = 16B row chunks)
    const unsigned short* Pq = P + pbase + h * 64;
    const unsigned short* Pk = Pq + DD;
    int rq[3];
#pragma unroll
    for (int t = 0; t < 3; t++) { int rr = t * 16 + l16; rq[t] = rr < 36 ? rr : 35; }

    f32x4 aff[3][3] = {};
#pragma unroll
    for (int ks = 0; ks < 64; ks += 32) {
        bf16x8 afr[3], bfr[3];
#pragma unroll
        for (int t = 0; t < 3; t++) afr[t] = *(const bf16x8*)&Pq[(size_t)rq[t] * NCOLS + ks + quad * 8];
#pragma unroll
        for (int t = 0; t < 3; t++) bfr[t] = *(const bf16x8*)&Pk[(size_t)rq[t] * NCOLS + ks + quad * 8];
#pragma unroll
        for (int mt = 0; mt < 3; mt++)
#pragma unroll
            for (int nt = 0; nt < 3; nt++)
                aff[mt][nt] = __builtin_amdgcn_mfma_f32_16x16x32_bf16(afr[mt], bfr[nt], aff[mt][nt], 0, 0, 0);
    }

    // softmax in regs (row = mt*16 + quad*4 + r, col = nt*16 + l16), att -> bf16 LDS (A-frag layout)
    const float* exb = extra + (size_t)blockIdx.x * 1296;
#pragma unroll
    for (int mt = 0; mt < 3; mt++) {
#pragma unroll
        for (int r = 0; r < 4; r++) {
            int row = mt * 16 + quad * 4 + r;
            float w[3];
#pragma unroll
            for (int nt = 0; nt < 3; nt++) {
                int col = nt * 16 + l16;
                bool valid = (row < 36) && (col < 36);
                w[nt] = valid ? (aff[mt][nt][r] * 0.125f + exb[row * 36 + col]) : -3.4e38f;
            }
            float mx = fmaxf(fmaxf(w[0], w[1]), w[2]);
#pragma unroll
            for (int d = 1; d < 16; d <<= 1) mx = fmaxf(mx, __shfl_xor(mx, d));
            float e0 = __expf(w[0] - mx), e1 = __expf(w[1] - mx), e2 = __expf(w[2] - mx);
            float s = e0 + e1 + e2;
#pragma unroll
            for (int d = 1; d < 16; d <<= 1) s += __shfl_xor(s, d);
            float rs = 1.0f / s;
            atts[row * 64 + 0  + l16] = f2bf(e0 * rs);
            atts[row * 64 + 16 + l16] = f2bf(e1 * rs);
            atts[row * 64 + 32 + l16] = f2bf(e2 * rs);
        }
    }
    __syncthreads();

    // PV: out_tile = att(36x64pad) @ vw(64pad x 64)
    f32x4 o[3][4] = {};
#pragma unroll
    for (int ks = 0; ks < 64; ks += 32) {
        bf16x8 pa[3], pb[4];
#pragma unroll
        for (int mt = 0; mt < 3; mt++) pa[mt] = *(const bf16x8*)&atts[(mt * 16 + l16) * 64 + ks + quad * 8];
#pragma unroll
        for (int nt = 0; nt < 4; nt++) pb[nt] = *(const bf16x8*)&vwT[(nt * 16 + l16) * 64 + ks + quad * 8];
#pragma unroll
        for (int mt = 0; mt < 3; mt++)
#pragma unroll
            for (int nt = 0; nt < 4; nt++)
                o[mt][nt] = __builtin_amdgcn_mfma_f32_16x16x32_bf16(pa[mt], pb[nt], o[mt][nt], 0, 0, 0);
    }

    float bo[4];
#pragma unroll
    for (int nt = 0; nt < 4; nt++) bo[nt] = bout[h * 64 + nt * 16 + l16];
#pragma unroll
    for (int mt = 0; mt < 3; mt++)
#pragma unroll
        for (int r = 0; r < 4; r++) {
            int n = mt * 16 + quad * 4 + r;
            if (n < 36) {
#pragma unroll
                for (int nt = 0; nt < 4; nt++)
                    out[(size_t)(b * NN + n) * DD + h * 64 + nt * 16 + l16] = o[mt][nt][r] + bo[nt];
            }
        }
}

// ---------------- launcher ----------------
extern "C" void kernel_launch(void* const* d_in, const int* in_sizes, int n_in,
                              void* d_out, int out_size, void* d_ws, size_t ws_size,
                              hipStream_t stream) {
    const float* roi  = (const float*)d_in[0];
    const int*   adj  = (const int*)  d_in[1];
    const float* pe   = (const float*)d_in[2];
    const float* lbl  = (const float*)d_in[3];
    const float* Wq   = (const float*)d_in[4];
    const float* bq   = (const float*)d_in[5];
    const float* Wk   = (const float*)d_in[6];
    const float* bk   = (const float*)d_in[7];
    const float* Wpos = (const float*)d_in[8];
    const float* bpos = (const float*)d_in[9];
    const float* Wout = (const float*)d_in[10];
    const float* bout = (const float*)d_in[11];
    float* out = (float*)d_out;

    char* w = (char*)d_ws;
    unsigned short* roi_bf  = (unsigned short*)(w);               // 4718592 bf16
    unsigned short* Wcat_bf = (unsigned short*)(w + 9437184);     // 3145728 bf16
    unsigned short* P       = (unsigned short*)(w + 15728640);    // 4608*3072 bf16
    float*          extra   = (float*)(w + 44040192);             // 128*16*36*36 f32

    cvt4_kernel<<<4608, 256, 0, stream>>>(roi,  roi_bf,  ROWS * DD / 4);
    cvt4_kernel<<<1024, 256, 0, stream>>>(Wq,   Wcat_bf,              DD * DD / 4);
    cvt4_kernel<<<1024, 256, 0, stream>>>(Wk,   Wcat_bf + DD * DD,    DD * DD / 4);
    cvt4_kernel<<<1024, 256, 0, stream>>>(Wout, Wcat_bf + 2 * DD * DD, DD * DD / 4);

    extra_kernel<<<648, 256, 0, stream>>>(pe, Wpos, bpos, adj, lbl, extra);

    gemm_kernel<<<36 * 24, 256, 0, stream>>>(roi_bf, Wcat_bf, bq, bk, P);

    attn_kernel<<<BB * HH, 64, 0, stream>>>(P, extra, bout, out);
}

// Round 3
// 213.379 us; speedup vs baseline: 1.1975x; 1.0185x over previous
//
#include <hip/hip_runtime.h>
#include <hip/hip_bf16.h>

#define BB 128
#define NN 36
#define DD 1024
#define HH 16
#define ROWS (BB*NN)          // 4608
#define NCOLS (3*DD)          // 3072: [q | k | vw]

typedef __attribute__((ext_vector_type(8))) __bf16 bf16x8;
typedef __attribute__((ext_vector_type(4))) float f32x4;
typedef __attribute__((ext_vector_type(4))) unsigned short us4;

__device__ inline unsigned short f2bf(float f) {
    __hip_bfloat16 h = __float2bfloat16(f);
    return *reinterpret_cast<unsigned short*>(&h);
}

__device__ inline void async16(const unsigned short* g, unsigned short* l) {
    __builtin_amdgcn_global_load_lds((const __attribute__((address_space(1))) unsigned int*)g,
                                     (__attribute__((address_space(3))) unsigned int*)l, 16, 0, 0);
}

// ---------------- fp32 -> bf16 convert, float4-vectorized ----------------
__global__ __launch_bounds__(256) void cvt4_kernel(const float* __restrict__ src,
                                                   unsigned short* __restrict__ dst, int n4) {
    int i = blockIdx.x * 256 + threadIdx.x;
    if (i < n4) {
        f32x4 v = ((const f32x4*)src)[i];
        us4 o;
        o.x = f2bf(v[0]); o.y = f2bf(v[1]); o.z = f2bf(v[2]); o.w = f2bf(v[3]);
        ((us4*)dst)[i] = o;
    }
}

// 3 weight matrices in one launch: grid 3072 blocks, 1024 per matrix
__global__ __launch_bounds__(256) void cvtW_kernel(const float* __restrict__ w0,
                                                   const float* __restrict__ w1,
                                                   const float* __restrict__ w2,
                                                   unsigned short* __restrict__ dst) {
    int sel = blockIdx.x >> 10;
    const float* src = sel == 0 ? w0 : (sel == 1 ? w1 : w2);
    int i = (blockIdx.x & 1023) * 256 + threadIdx.x;   // < 262144 = DD*DD/4
    f32x4 v = ((const f32x4*)src)[i];
    us4 o;
    o.x = f2bf(v[0]); o.y = f2bf(v[1]); o.z = f2bf(v[2]); o.w = f2bf(v[3]);
    ((us4*)(dst + (size_t)sel * DD * DD))[i] = o;
}

// ---------------- GEMM: P(4608x3072 bf16) = roi_bf @ Wcat_bf^T + [bq|bk|0] ----------------
// 128x128 tile, BK=64, XOR-swizzled LDS (swizzle folded into global source col),
// global_load_lds width=16. 4 waves x (4x4 MFMA 16x16x32) x 2 k-steps per barrier.
__global__ __launch_bounds__(256) void gemm_kernel(const unsigned short* __restrict__ A,
                                                   const unsigned short* __restrict__ Bm,
                                                   const float* __restrict__ bq,
                                                   const float* __restrict__ bk,
                                                   unsigned short* __restrict__ P) {
    __shared__ __align__(16) unsigned short As[128 * 64];
    __shared__ __align__(16) unsigned short Bs[128 * 64];
    const int tid  = threadIdx.x;
    const int m0   = (blockIdx.x % 36) * 128;
    const int n0   = (blockIdx.x / 36) * 128;
    const int wave = tid >> 6, lane = tid & 63;
    const int quad = lane >> 4, l16 = lane & 15;
    const int wm = (wave & 1) * 64, wn = (wave >> 1) * 64;

    // staging: 1024 chunks of 8 elems per 128x64 tile; chunk c -> row=c>>3, sw-col=(c&7)
    // LDS holds sw-col at linear pos; global col = (swcol ^ (row&7)) * 8
    int crow[4], ccol[4];
#pragma unroll
    for (int p = 0; p < 4; p++) {
        int c = wave * 256 + p * 64 + lane;
        crow[p] = c >> 3;
        ccol[p] = ((c & 7) ^ (crow[p] & 7)) * 8;
    }

    f32x4 acc[4][4] = {};

    for (int k0 = 0; k0 < DD; k0 += 64) {
#pragma unroll
        for (int p = 0; p < 4; p++) {
            async16(A  + (size_t)(m0 + crow[p]) * DD + k0 + ccol[p], As + wave * 2048 + p * 512);
            async16(Bm + (size_t)(n0 + crow[p]) * DD + k0 + ccol[p], Bs + wave * 2048 + p * 512);
        }
        __syncthreads();

#pragma unroll
        for (int ks = 0; ks < 2; ks++) {
            bf16x8 af[4], bf[4];
#pragma unroll
            for (int mi = 0; mi < 4; mi++) {
                int row = wm + mi * 16 + l16;
                int kch = ks * 4 + quad;
                af[mi] = *(const bf16x8*)&As[row * 64 + ((kch ^ (row & 7)) * 8)];
            }
#pragma unroll
            for (int ni = 0; ni < 4; ni++) {
                int row = wn + ni * 16 + l16;
                int kch = ks * 4 + quad;
                bf[ni] = *(const bf16x8*)&Bs[row * 64 + ((kch ^ (row & 7)) * 8)];
            }
#pragma unroll
            for (int mi = 0; mi < 4; mi++)
#pragma unroll
                for (int ni = 0; ni < 4; ni++)
                    acc[mi][ni] = __builtin_amdgcn_mfma_f32_16x16x32_bf16(af[mi], bf[ni], acc[mi][ni], 0, 0, 0);
        }
        __syncthreads();
    }

#pragma unroll
    for (int mi = 0; mi < 4; mi++)
#pragma unroll
        for (int ni = 0; ni < 4; ni++) {
            int row = m0 + wm + mi * 16 + quad * 4;
            int col = n0 + wn + ni * 16 + l16;
            float bc = (col < DD) ? bq[col] : ((col < 2 * DD) ? bk[col - DD] : 0.f);
#pragma unroll
            for (int r = 0; r < 4; r++)
                P[(size_t)(row + r) * NCOLS + col] = f2bf(acc[mi][ni][r] + bc);
        }
}

// ---------------- extra[b,h,n,m] = log(max(relu(pe.Wpos[h]+bpos[h]),1e-6)) + mask + lbl ------
__global__ __launch_bounds__(256) void extra_kernel(const float* __restrict__ pe,
                                                    const float* __restrict__ Wpos,
                                                    const float* __restrict__ bpos,
                                                    const int* __restrict__ adj,
                                                    const float* __restrict__ lbl,
                                                    float* __restrict__ extra) {
    __shared__ __align__(16) float wps[HH * 64];
    __shared__ float bps[HH];
    int tid = threadIdx.x;
    for (int i = tid; i < HH * 64; i += 256) wps[i] = Wpos[i];
    if (tid < HH) bps[tid] = bpos[tid];
    __syncthreads();

    int idx = blockIdx.x * 256 + tid;             // one (b,n,m); grid covers 165888
    f32x4 pr[16];
    const f32x4* pv = (const f32x4*)(pe + (size_t)idx * 64);
#pragma unroll
    for (int j = 0; j < 16; j++) pr[j] = pv[j];
    int a = adj[idx];
    float add = lbl[idx] + (a > 0 ? 0.f : -9e15f);
    int b = idx / 1296, nm = idx % 1296;
    size_t obase = (size_t)b * (16 * 1296) + (nm % 36) + (size_t)(nm / 36) * 36;
    for (int hh = 0; hh < 16; hh++) {
        const f32x4* wv = (const f32x4*)(wps + hh * 64);
        f32x4 acc4 = {0.f, 0.f, 0.f, 0.f};
#pragma unroll
        for (int j = 0; j < 16; j++) acc4 += pr[j] * wv[j];
        float d = acc4[0] + acc4[1] + acc4[2] + acc4[3] + bps[hh];
        d = fmaxf(d, 0.f);
        d = __logf(fmaxf(d, 1e-6f));
        extra[obase + (size_t)hh * 1296] = d + add;
    }
}

// ---------------- fused MFMA attention: one wave per (b,h) ----------------
#define VS 72   // padded LDS stride in shorts (144 B: 16B-aligned rows, conflict-free)
__global__ __launch_bounds__(64) void attn_kernel(const unsigned short* __restrict__ P,
                                                  const float* __restrict__ extra,
                                                  const float* __restrict__ bout,
                                                  float* __restrict__ out) {
    const int b = blockIdx.x >> 4;
    const int h = blockIdx.x & 15;
    __shared__ __align__(16) unsigned short vwT[64 * VS];   // [e][m], m in [36,64) zeroed
    __shared__ __align__(16) unsigned short atts[48 * VS];  // [n][m] bf16 att
    __shared__ __align__(16) float exs[1296];
    const int lane = threadIdx.x;
    const int quad = lane >> 4, l16 = lane & 15;
    const size_t pbase = (size_t)b * NN * NCOLS;

    // 1) issue vw + extra loads into regs first (overlap with QK below)
    us4 vreg[9];
#pragma unroll
    for (int i = 0; i < 9; i++) {
        int idx = i * 64 + lane;
        int m = idx >> 4, e0 = (idx & 15) * 4;
        vreg[i] = *(const us4*)&P[pbase + (size_t)m * NCOLS + 2 * DD + h * 64 + e0];
    }
    const f32x4* exg = (const f32x4*)(extra + (size_t)blockIdx.x * 1296);
    f32x4 ereg[6];
#pragma unroll
    for (int i = 0; i < 6; i++) {
        int idx = i * 64 + lane;
        if (idx < 324) ereg[i] = exg[idx];
    }

    // 2) QK^T: fragments straight from global (A-frag = 16B row chunks)
    const unsigned short* Pq = P + pbase + h * 64;
    const unsigned short* Pk = Pq + DD;
    int rq[3];
#pragma unroll
    for (int t = 0; t < 3; t++) { int rr = t * 16 + l16; rq[t] = rr < 36 ? rr : 35; }

    f32x4 aff[3][3] = {};
#pragma unroll
    for (int ks = 0; ks < 64; ks += 32) {
        bf16x8 afr[3], bfr[3];
#pragma unroll
        for (int t = 0; t < 3; t++) afr[t] = *(const bf16x8*)&Pq[(size_t)rq[t] * NCOLS + ks + quad * 8];
#pragma unroll
        for (int t = 0; t < 3; t++) bfr[t] = *(const bf16x8*)&Pk[(size_t)rq[t] * NCOLS + ks + quad * 8];
#pragma unroll
        for (int mt = 0; mt < 3; mt++)
#pragma unroll
            for (int nt = 0; nt < 3; nt++)
                aff[mt][nt] = __builtin_amdgcn_mfma_f32_16x16x32_bf16(afr[mt], bfr[nt], aff[mt][nt], 0, 0, 0);
    }

    // 3) spill staged data to LDS; zero pads
    for (int i = lane; i < 64 * 28; i += 64) vwT[(i / 28) * VS + 36 + (i % 28)] = 0;   // m 36..63
    for (int i = lane; i < 48 * 16; i += 64) atts[(i >> 4) * VS + 48 + (i & 15)] = 0;  // m 48..63
#pragma unroll
    for (int i = 0; i < 9; i++) {
        int idx = i * 64 + lane;
        int m = idx >> 4, e0 = (idx & 15) * 4;
        vwT[(e0 + 0) * VS + m] = vreg[i].x;
        vwT[(e0 + 1) * VS + m] = vreg[i].y;
        vwT[(e0 + 2) * VS + m] = vreg[i].z;
        vwT[(e0 + 3) * VS + m] = vreg[i].w;
    }
#pragma unroll
    for (int i = 0; i < 6; i++) {
        int idx = i * 64 + lane;
        if (idx < 324) ((f32x4*)exs)[idx] = ereg[i];
    }
    __syncthreads();

    // 4) softmax in regs (row = mt*16+quad*4+r, col = nt*16+l16) -> bf16 atts
#pragma unroll
    for (int mt = 0; mt < 3; mt++) {
#pragma unroll
        for (int r = 0; r < 4; r++) {
            int row = mt * 16 + quad * 4 + r;
            float w[3];
#pragma unroll
            for (int nt = 0; nt < 3; nt++) {
                int col = nt * 16 + l16;
                bool valid = (row < 36) && (col < 36);
                w[nt] = valid ? (aff[mt][nt][r] * 0.125f + exs[row * 36 + col]) : -3.4e38f;
            }
            float mx = fmaxf(fmaxf(w[0], w[1]), w[2]);
#pragma unroll
            for (int d = 1; d < 16; d <<= 1) mx = fmaxf(mx, __shfl_xor(mx, d));
            float e0 = __expf(w[0] - mx), e1 = __expf(w[1] - mx), e2 = __expf(w[2] - mx);
            float s = e0 + e1 + e2;
#pragma unroll
            for (int d = 1; d < 16; d <<= 1) s += __shfl_xor(s, d);
            float rs = 1.0f / s;
            atts[row * VS + 0  + l16] = f2bf(e0 * rs);
            atts[row * VS + 16 + l16] = f2bf(e1 * rs);
            atts[row * VS + 32 + l16] = f2bf(e2 * rs);
        }
    }
    __syncthreads();

    // 5) PV: out_tile = att(36x64pad) @ vwT^T
    f32x4 o[3][4] = {};
#pragma unroll
    for (int ks = 0; ks < 64; ks += 32) {
        bf16x8 pa[3], pb[4];
#pragma unroll
        for (int mt = 0; mt < 3; mt++) pa[mt] = *(const bf16x8*)&atts[(mt * 16 + l16) * VS + ks + quad * 8];
#pragma unroll
        for (int nt = 0; nt < 4; nt++) pb[nt] = *(const bf16x8*)&vwT[(nt * 16 + l16) * VS + ks + quad * 8];
#pragma unroll
        for (int mt = 0; mt < 3; mt++)
#pragma unroll
            for (int nt = 0; nt < 4; nt++)
                o[mt][nt] = __builtin_amdgcn_mfma_f32_16x16x32_bf16(pa[mt], pb[nt], o[mt][nt], 0, 0, 0);
    }

    float bo[4];
#pragma unroll
    for (int nt = 0; nt < 4; nt++) bo[nt] = bout[h * 64 + nt * 16 + l16];
#pragma unroll
    for (int mt = 0; mt < 3; mt++)
#pragma unroll
        for (int r = 0; r < 4; r++) {
            int n = mt * 16 + quad * 4 + r;
            if (n < 36) {
#pragma unroll
                for (int nt = 0; nt < 4; nt++)
                    out[(size_t)(b * NN + n) * DD + h * 64 + nt * 16 + l16] = o[mt][nt][r] + bo[nt];
            }
        }
}

// ---------------- launcher ----------------
extern "C" void kernel_launch(void* const* d_in, const int* in_sizes, int n_in,
                              void* d_out, int out_size, void* d_ws, size_t ws_size,
                              hipStream_t stream) {
    const float* roi  = (const float*)d_in[0];
    const int*   adj  = (const int*)  d_in[1];
    const float* pe   = (const float*)d_in[2];
    const float* lbl  = (const float*)d_in[3];
    const float* Wq   = (const float*)d_in[4];
    const float* bq   = (const float*)d_in[5];
    const float* Wk   = (const float*)d_in[6];
    const float* bk   = (const float*)d_in[7];
    const float* Wpos = (const float*)d_in[8];
    const float* bpos = (const float*)d_in[9];
    const float* Wout = (const float*)d_in[10];
    const float* bout = (const float*)d_in[11];
    float* out = (float*)d_out;

    char* w = (char*)d_ws;
    unsigned short* roi_bf  = (unsigned short*)(w);               // 4718592 bf16
    unsigned short* Wcat_bf = (unsigned short*)(w + 9437184);     // 3145728 bf16
    unsigned short* P       = (unsigned short*)(w + 15728640);    // 4608*3072 bf16
    float*          extra   = (float*)(w + 44040192);             // 128*16*36*36 f32

    cvt4_kernel<<<4608, 256, 0, stream>>>(roi, roi_bf, ROWS * DD / 4);
    cvtW_kernel<<<3072, 256, 0, stream>>>(Wq, Wk, Wout, Wcat_bf);

    extra_kernel<<<648, 256, 0, stream>>>(pe, Wpos, bpos, adj, lbl, extra);

    gemm_kernel<<<36 * 24, 256, 0, stream>>>(roi_bf, Wcat_bf, bq, bk, P);

    attn_kernel<<<BB * HH, 64, 0, stream>>>(P, extra, bout, out);
}

// Round 4
// 203.714 us; speedup vs baseline: 1.2544x; 1.0474x over previous
//
#include <hip/hip_runtime.h>
#include <hip/hip_bf16.h>

#define BB 128
#define NN 36
#define DD 1024
#define HH 16
#define ROWS (BB*NN)          // 4608
#define NCOLS (3*DD)          // 3072: [q | k | vw]

typedef __attribute__((ext_vector_type(8))) __bf16 bf16x8;
typedef __attribute__((ext_vector_type(4))) float f32x4;
typedef __attribute__((ext_vector_type(4))) unsigned short us4;
typedef __attribute__((ext_vector_type(8))) unsigned short us8;

__device__ inline unsigned short f2bf(float f) {
    __hip_bfloat16 h = __float2bfloat16(f);
    return *reinterpret_cast<unsigned short*>(&h);
}

__device__ inline void async16(const unsigned short* g, unsigned short* l) {
    __builtin_amdgcn_global_load_lds((const __attribute__((address_space(1))) unsigned int*)g,
                                     (__attribute__((address_space(3))) unsigned int*)l, 16, 0, 0);
}

// ---------------- prep: roi->bf16, W->bf16, extra  (one launch) ----------------
// grid: [0,4608) roi cvt | [4608,7680) weight cvt | [7680,8328) extra
__global__ __launch_bounds__(256) void prep_kernel(const float* __restrict__ roi,
                                                   const float* __restrict__ Wq,
                                                   const float* __restrict__ Wk,
                                                   const float* __restrict__ Wout,
                                                   const float* __restrict__ pe,
                                                   const float* __restrict__ Wpos,
                                                   const float* __restrict__ bpos,
                                                   const int* __restrict__ adj,
                                                   const float* __restrict__ lbl,
                                                   unsigned short* __restrict__ roi_bf,
                                                   unsigned short* __restrict__ Wcat_bf,
                                                   float* __restrict__ extra) {
    const int bid = blockIdx.x, tid = threadIdx.x;
    if (bid < 4608) {
        int i = bid * 256 + tid;                  // < 1179648 = ROWS*DD/4
        f32x4 v = ((const f32x4*)roi)[i];
        us4 o;
        o.x = f2bf(v[0]); o.y = f2bf(v[1]); o.z = f2bf(v[2]); o.w = f2bf(v[3]);
        ((us4*)roi_bf)[i] = o;
        return;
    }
    if (bid < 7680) {
        int wb = bid - 4608;
        int sel = wb >> 10;
        const float* src = sel == 0 ? Wq : (sel == 1 ? Wk : Wout);
        int i = (wb & 1023) * 256 + tid;          // < 262144
        f32x4 v = ((const f32x4*)src)[i];
        us4 o;
        o.x = f2bf(v[0]); o.y = f2bf(v[1]); o.z = f2bf(v[2]); o.w = f2bf(v[3]);
        ((us4*)(Wcat_bf + (size_t)sel * DD * DD))[i] = o;
        return;
    }
    // ---- extra: [b,h,n,m] = log(max(relu(pe.Wpos[h]+bpos[h]),1e-6)) + mask + lbl ----
    __shared__ __align__(16) float wps[HH * 64];
    __shared__ float bps[HH];
    for (int i = tid; i < HH * 64; i += 256) wps[i] = Wpos[i];
    if (tid < HH) bps[tid] = bpos[tid];
    __syncthreads();

    int idx = (bid - 7680) * 256 + tid;           // one (b,n,m); 165888 total
    f32x4 pr[16];
    const f32x4* pv = (const f32x4*)(pe + (size_t)idx * 64);
#pragma unroll
    for (int j = 0; j < 16; j++) pr[j] = pv[j];
    int a = adj[idx];
    float add = lbl[idx] + (a > 0 ? 0.f : -9e15f);
    int b = idx / 1296, nm = idx % 1296;
    size_t obase = (size_t)b * (16 * 1296) + nm;
    for (int hh = 0; hh < 16; hh++) {
        const f32x4* wv = (const f32x4*)(wps + hh * 64);
        f32x4 acc4 = {0.f, 0.f, 0.f, 0.f};
#pragma unroll
        for (int j = 0; j < 16; j++) acc4 += pr[j] * wv[j];
        float d = acc4[0] + acc4[1] + acc4[2] + acc4[3] + bps[hh];
        d = fmaxf(d, 0.f);
        d = __logf(fmaxf(d, 1e-6f));
        extra[obase + (size_t)hh * 1296] = d + add;
    }
}

// ---------------- GEMM: P(4608x3072 bf16) = roi_bf @ Wcat_bf^T + [bq|bk|0] ----------------
// 128x64 tile, BK=64, XOR-swizzled LDS, global_load_lds w16, coalesced LDS-staged epilogue.
__global__ __launch_bounds__(256) void gemm_kernel(const unsigned short* __restrict__ A,
                                                   const unsigned short* __restrict__ Bm,
                                                   const float* __restrict__ bq,
                                                   const float* __restrict__ bk,
                                                   unsigned short* __restrict__ P) {
    __shared__ __align__(16) unsigned short smem[12288];   // 24576 B
    unsigned short* As = smem;            // 128x64 = 16384 B
    unsigned short* Bs = smem + 8192;     // 64x64  =  8192 B
    unsigned short* Cs = smem;            // epilogue reuse: 128x72 = 18432 B

    const int tid  = threadIdx.x;
    const int n0   = (blockIdx.x % 48) * 64;
    const int m0   = (blockIdx.x / 48) * 128;
    const int wave = tid >> 6, lane = tid & 63;
    const int quad = lane >> 4, l16 = lane & 15;
    const int wm = (wave & 1) * 64, wn = (wave >> 1) * 32;

    // A: 1024 chunks (128 rows x 8), 4/thread; B: 512 chunks (64 x 8), 2/thread
    int arow[4], acol[4], brow[2], bcol[2];
#pragma unroll
    for (int p = 0; p < 4; p++) {
        int c = wave * 256 + p * 64 + lane;
        arow[p] = c >> 3;
        acol[p] = ((c & 7) ^ (arow[p] & 7)) * 8;
    }
#pragma unroll
    for (int p = 0; p < 2; p++) {
        int c = wave * 128 + p * 64 + lane;
        brow[p] = c >> 3;
        bcol[p] = ((c & 7) ^ (brow[p] & 7)) * 8;
    }

    f32x4 acc[4][2] = {};

    for (int k0 = 0; k0 < DD; k0 += 64) {
#pragma unroll
        for (int p = 0; p < 4; p++)
            async16(A + (size_t)(m0 + arow[p]) * DD + k0 + acol[p], As + wave * 2048 + p * 512);
#pragma unroll
        for (int p = 0; p < 2; p++)
            async16(Bm + (size_t)(n0 + brow[p]) * DD + k0 + bcol[p], Bs + wave * 1024 + p * 512);
        __syncthreads();

#pragma unroll
        for (int ks = 0; ks < 2; ks++) {
            int kch = ks * 4 + quad;
            bf16x8 af[4], bf[2];
#pragma unroll
            for (int mi = 0; mi < 4; mi++) {
                int row = wm + mi * 16 + l16;
                af[mi] = *(const bf16x8*)&As[row * 64 + ((kch ^ (row & 7)) * 8)];
            }
#pragma unroll
            for (int ni = 0; ni < 2; ni++) {
                int row = wn + ni * 16 + l16;
                bf[ni] = *(const bf16x8*)&Bs[row * 64 + ((kch ^ (row & 7)) * 8)];
            }
#pragma unroll
            for (int mi = 0; mi < 4; mi++)
#pragma unroll
                for (int ni = 0; ni < 2; ni++)
                    acc[mi][ni] = __builtin_amdgcn_mfma_f32_16x16x32_bf16(af[mi], bf[ni], acc[mi][ni], 0, 0, 0);
        }
        __syncthreads();
    }

    // epilogue: acc -> Cs (bf16, stride 72) -> coalesced us8 global stores
    float bias[2];
#pragma unroll
    for (int ni = 0; ni < 2; ni++) {
        int colg = n0 + wn + ni * 16 + l16;
        bias[ni] = (colg < DD) ? bq[colg] : ((colg < 2 * DD) ? bk[colg - DD] : 0.f);
    }
#pragma unroll
    for (int mi = 0; mi < 4; mi++)
#pragma unroll
        for (int ni = 0; ni < 2; ni++) {
            int row = wm + mi * 16 + quad * 4;
            int col = wn + ni * 16 + l16;
#pragma unroll
            for (int r = 0; r < 4; r++)
                Cs[(row + r) * 72 + col] = f2bf(acc[mi][ni][r] + bias[ni]);
        }
    __syncthreads();
#pragma unroll
    for (int i = 0; i < 4; i++) {
        int ch = i * 256 + tid;            // 1024 chunks of 8 shorts
        int row = ch >> 3, cc = (ch & 7) * 8;
        us8 v = *(const us8*)&Cs[row * 72 + cc];
        *(us8*)&P[(size_t)(m0 + row) * NCOLS + n0 + cc] = v;
    }
}

// ---------------- fused MFMA attention: one wave per (b,h) ----------------
#define VS 72
__global__ __launch_bounds__(64) void attn_kernel(const unsigned short* __restrict__ P,
                                                  const float* __restrict__ extra,
                                                  const float* __restrict__ bout,
                                                  float* __restrict__ out) {
    const int b = blockIdx.x >> 4;
    const int h = blockIdx.x & 15;
    __shared__ __align__(16) unsigned short smem_att[(64 + 48) * VS];  // vwT | atts, 16128 B
    __shared__ __align__(16) float exs[1296];
    unsigned short* vwT  = smem_att;            // [e][m] 64xVS
    unsigned short* atts = smem_att + 64 * VS;  // [n][m] 48xVS
    float* osT = (float*)smem_att;              // epilogue reuse: 36x68 f32 = 9792 B
    const int lane = threadIdx.x;
    const int quad = lane >> 4, l16 = lane & 15;
    const size_t pbase = (size_t)b * NN * NCOLS;

    // 1) prefetch vw + extra into regs
    us4 vreg[9];
#pragma unroll
    for (int i = 0; i < 9; i++) {
        int idx = i * 64 + lane;
        int m = idx >> 4, e0 = (idx & 15) * 4;
        vreg[i] = *(const us4*)&P[pbase + (size_t)m * NCOLS + 2 * DD + h * 64 + e0];
    }
    const f32x4* exg = (const f32x4*)(extra + (size_t)blockIdx.x * 1296);
    f32x4 ereg[6];
#pragma unroll
    for (int i = 0; i < 6; i++) {
        int idx = i * 64 + lane;
        if (idx < 324) ereg[i] = exg[idx];
    }

    // 2) QK^T: frags straight from global
    const unsigned short* Pq = P + pbase + h * 64;
    const unsigned short* Pk = Pq + DD;
    int rq[3];
#pragma unroll
    for (int t = 0; t < 3; t++) { int rr = t * 16 + l16; rq[t] = rr < 36 ? rr : 35; }

    f32x4 aff[3][3] = {};
#pragma unroll
    for (int ks = 0; ks < 64; ks += 32) {
        bf16x8 afr[3], bfr[3];
#pragma unroll
        for (int t = 0; t < 3; t++) afr[t] = *(const bf16x8*)&Pq[(size_t)rq[t] * NCOLS + ks + quad * 8];
#pragma unroll
        for (int t = 0; t < 3; t++) bfr[t] = *(const bf16x8*)&Pk[(size_t)rq[t] * NCOLS + ks + quad * 8];
#pragma unroll
        for (int mt = 0; mt < 3; mt++)
#pragma unroll
            for (int nt = 0; nt < 3; nt++)
                aff[mt][nt] = __builtin_amdgcn_mfma_f32_16x16x32_bf16(afr[mt], bfr[nt], aff[mt][nt], 0, 0, 0);
    }

    // 3) spill vw/extra to LDS; zero pads
    for (int i = lane; i < 64 * 28; i += 64) vwT[(i / 28) * VS + 36 + (i % 28)] = 0;
    for (int i = lane; i < 48 * 16; i += 64) atts[(i >> 4) * VS + 48 + (i & 15)] = 0;
#pragma unroll
    for (int i = 0; i < 9; i++) {
        int idx = i * 64 + lane;
        int m = idx >> 4, e0 = (idx & 15) * 4;
        vwT[(e0 + 0) * VS + m] = vreg[i].x;
        vwT[(e0 + 1) * VS + m] = vreg[i].y;
        vwT[(e0 + 2) * VS + m] = vreg[i].z;
        vwT[(e0 + 3) * VS + m] = vreg[i].w;
    }
#pragma unroll
    for (int i = 0; i < 6; i++) {
        int idx = i * 64 + lane;
        if (idx < 324) ((f32x4*)exs)[idx] = ereg[i];
    }
    __syncthreads();

    // 4) softmax (row = mt*16+quad*4+r, col = nt*16+l16) -> bf16 atts (A-frag layout)
#pragma unroll
    for (int mt = 0; mt < 3; mt++) {
#pragma unroll
        for (int r = 0; r < 4; r++) {
            int row = mt * 16 + quad * 4 + r;
            float w[3];
#pragma unroll
            for (int nt = 0; nt < 3; nt++) {
                int col = nt * 16 + l16;
                bool valid = (row < 36) && (col < 36);
                w[nt] = valid ? (aff[mt][nt][r] * 0.125f + exs[row * 36 + col]) : -3.4e38f;
            }
            float mx = fmaxf(fmaxf(w[0], w[1]), w[2]);
#pragma unroll
            for (int d = 1; d < 16; d <<= 1) mx = fmaxf(mx, __shfl_xor(mx, d));
            float e0 = __expf(w[0] - mx), e1 = __expf(w[1] - mx), e2 = __expf(w[2] - mx);
            float s = e0 + e1 + e2;
#pragma unroll
            for (int d = 1; d < 16; d <<= 1) s += __shfl_xor(s, d);
            float rs = 1.0f / s;
            atts[row * VS + 0  + l16] = f2bf(e0 * rs);
            atts[row * VS + 16 + l16] = f2bf(e1 * rs);
            atts[row * VS + 32 + l16] = f2bf(e2 * rs);
        }
    }
    __syncthreads();

    // 5) PV
    f32x4 o[3][4] = {};
#pragma unroll
    for (int ks = 0; ks < 64; ks += 32) {
        bf16x8 pa[3], pb[4];
#pragma unroll
        for (int mt = 0; mt < 3; mt++) pa[mt] = *(const bf16x8*)&atts[(mt * 16 + l16) * VS + ks + quad * 8];
#pragma unroll
        for (int nt = 0; nt < 4; nt++) pb[nt] = *(const bf16x8*)&vwT[(nt * 16 + l16) * VS + ks + quad * 8];
#pragma unroll
        for (int mt = 0; mt < 3; mt++)
#pragma unroll
            for (int nt = 0; nt < 4; nt++)
                o[mt][nt] = __builtin_amdgcn_mfma_f32_16x16x32_bf16(pa[mt], pb[nt], o[mt][nt], 0, 0, 0);
    }
    __syncthreads();   // vwT/atts dead; reuse as osT

    // 6) epilogue: o -> osT (f32, stride 68) -> coalesced f32x4 stores
    float bo[4];
#pragma unroll
    for (int nt = 0; nt < 4; nt++) bo[nt] = bout[h * 64 + nt * 16 + l16];
#pragma unroll
    for (int mt = 0; mt < 3; mt++)
#pragma unroll
        for (int r = 0; r < 4; r++) {
            int n = mt * 16 + quad * 4 + r;
            if (n < 36) {
#pragma unroll
                for (int nt = 0; nt < 4; nt++)
                    osT[n * 68 + nt * 16 + l16] = o[mt][nt][r] + bo[nt];
            }
        }
    __syncthreads();
#pragma unroll
    for (int i = 0; i < 9; i++) {
        int ch = i * 64 + lane;            // 576 chunks of f32x4
        int n = ch >> 4, c = (ch & 15) * 4;
        f32x4 v = *(const f32x4*)&osT[n * 68 + c];
        *(f32x4*)&out[(size_t)(b * NN + n) * DD + h * 64 + c] = v;
    }
}

// ---------------- launcher ----------------
extern "C" void kernel_launch(void* const* d_in, const int* in_sizes, int n_in,
                              void* d_out, int out_size, void* d_ws, size_t ws_size,
                              hipStream_t stream) {
    const float* roi  = (const float*)d_in[0];
    const int*   adj  = (const int*)  d_in[1];
    const float* pe   = (const float*)d_in[2];
    const float* lbl  = (const float*)d_in[3];
    const float* Wq   = (const float*)d_in[4];
    const float* bq   = (const float*)d_in[5];
    const float* Wk   = (const float*)d_in[6];
    const float* bk   = (const float*)d_in[7];
    const float* Wpos = (const float*)d_in[8];
    const float* bpos = (const float*)d_in[9];
    const float* Wout = (const float*)d_in[10];
    const float* bout = (const float*)d_in[11];
    float* out = (float*)d_out;

    char* w = (char*)d_ws;
    unsigned short* roi_bf  = (unsigned short*)(w);               // 9.4 MB
    unsigned short* Wcat_bf = (unsigned short*)(w + 9437184);     // 6.3 MB
    unsigned short* P       = (unsigned short*)(w + 15728640);    // 28.3 MB
    float*          extra   = (float*)(w + 44040192);             // 10.6 MB

    prep_kernel<<<8328, 256, 0, stream>>>(roi, Wq, Wk, Wout, pe, Wpos, bpos, adj, lbl,
                                          roi_bf, Wcat_bf, extra);
    gemm_kernel<<<36 * 48, 256, 0, stream>>>(roi_bf, Wcat_bf, bq, bk, P);
    attn_kernel<<<BB * HH, 64, 0, stream>>>(P, extra, bout, out);
}

// Round 5
// 177.904 us; speedup vs baseline: 1.4363x; 1.1451x over previous
//
#include <hip/hip_runtime.h>
#include <hip/hip_bf16.h>

#define BB 128
#define NN 36
#define DD 1024
#define HH 16
#define ROWS (BB*NN)          // 4608

typedef __attribute__((ext_vector_type(8))) __bf16 bf16x8;
typedef __attribute__((ext_vector_type(4))) float f32x4;
typedef __attribute__((ext_vector_type(4))) unsigned short us4;

__device__ inline unsigned short f2bf(float f) {
    __hip_bfloat16 h = __float2bfloat16(f);
    return *reinterpret_cast<unsigned short*>(&h);
}

__device__ inline void async16(const unsigned short* g, unsigned short* l) {
    __builtin_amdgcn_global_load_lds((const __attribute__((address_space(1))) unsigned int*)g,
                                     (__attribute__((address_space(3))) unsigned int*)l, 16, 0, 0);
}

// ---------------- prep: roi->bf16, W->bf16, extra  (one launch) ----------------
// grid: [0,4608) roi cvt | [4608,7680) weight cvt | [7680,8328) extra
__global__ __launch_bounds__(256) void prep_kernel(const float* __restrict__ roi,
                                                   const float* __restrict__ Wq,
                                                   const float* __restrict__ Wk,
                                                   const float* __restrict__ Wout,
                                                   const float* __restrict__ pe,
                                                   const float* __restrict__ Wpos,
                                                   const float* __restrict__ bpos,
                                                   const int* __restrict__ adj,
                                                   const float* __restrict__ lbl,
                                                   unsigned short* __restrict__ roi_bf,
                                                   unsigned short* __restrict__ Wcat_bf,
                                                   float* __restrict__ extra) {
    const int bid = blockIdx.x, tid = threadIdx.x;
    if (bid < 4608) {
        int i = bid * 256 + tid;
        f32x4 v = ((const f32x4*)roi)[i];
        us4 o;
        o.x = f2bf(v[0]); o.y = f2bf(v[1]); o.z = f2bf(v[2]); o.w = f2bf(v[3]);
        ((us4*)roi_bf)[i] = o;
        return;
    }
    if (bid < 7680) {
        int wb = bid - 4608;
        int sel = wb >> 10;
        const float* src = sel == 0 ? Wq : (sel == 1 ? Wk : Wout);
        int i = (wb & 1023) * 256 + tid;
        f32x4 v = ((const f32x4*)src)[i];
        us4 o;
        o.x = f2bf(v[0]); o.y = f2bf(v[1]); o.z = f2bf(v[2]); o.w = f2bf(v[3]);
        ((us4*)(Wcat_bf + (size_t)sel * DD * DD))[i] = o;
        return;
    }
    __shared__ __align__(16) float wps[HH * 64];
    __shared__ float bps[HH];
    for (int i = tid; i < HH * 64; i += 256) wps[i] = Wpos[i];
    if (tid < HH) bps[tid] = bpos[tid];
    __syncthreads();

    int idx = (bid - 7680) * 256 + tid;           // one (b,n,m); 165888 total
    f32x4 pr[16];
    const f32x4* pv = (const f32x4*)(pe + (size_t)idx * 64);
#pragma unroll
    for (int j = 0; j < 16; j++) pr[j] = pv[j];
    int a = adj[idx];
    float add = lbl[idx] + (a > 0 ? 0.f : -9e15f);
    int b = idx / 1296, nm = idx % 1296;
    size_t obase = (size_t)b * (16 * 1296) + nm;
    for (int hh = 0; hh < 16; hh++) {
        const f32x4* wv = (const f32x4*)(wps + hh * 64);
        f32x4 acc4 = {0.f, 0.f, 0.f, 0.f};
#pragma unroll
        for (int j = 0; j < 16; j++) acc4 += pr[j] * wv[j];
        float d = acc4[0] + acc4[1] + acc4[2] + acc4[3] + bps[hh];
        d = fmaxf(d, 0.f);
        d = __logf(fmaxf(d, 1e-6f));
        extra[obase + (size_t)hh * 1296] = d + add;
    }
}

// ---------------- fused GEMM + attention: one block per (4-batch group, head) ----------------
// GEMM tile: M=144 (4 batches x 36 rows, no padding; 144=9x16), N=192 ([q|k|vw] head slices),
// K=1024. Then per-wave attention for one batch each. No P materialization.
__global__ __launch_bounds__(256, 2) void fused_kernel(const unsigned short* __restrict__ A,
                                                       const unsigned short* __restrict__ Wc,
                                                       const float* __restrict__ bq,
                                                       const float* __restrict__ bk,
                                                       const float* __restrict__ extra,
                                                       const float* __restrict__ bout,
                                                       float* __restrict__ out) {
    __shared__ __align__(16) unsigned short pool[32256];   // 64512 B
    const int tid  = threadIdx.x;
    const int wave = tid >> 6, lane = tid & 63;
    const int quad = lane >> 4, l16 = lane & 15;
    const int h  = blockIdx.x & 15;
    const int bg = blockIdx.x >> 4;            // 0..31, 4 batches each
    const int row0 = bg * 144;

    unsigned short* As = pool;                 // [144][64] bf16, XOR-swizzled
    unsigned short* Bs = pool + 9216;          // [192][64] bf16, XOR-swizzled

    // ---------------- K loop ----------------
    f32x4 acc[9][3] = {};                      // rows rt*16, wave's 48-col slice ct*16
    const int cnt = (wave < 2) ? 11 : 10;      // staging instrs per wave (42 total)

    for (int k0 = 0; k0 < DD; k0 += 64) {
        for (int i = 0; i < cnt; i++) {
            int j = wave + 4 * i;              // 0..41, each covers 64 chunks of 8 bf16
            int c = j * 64 + lane;
            if (j < 18) {                      // A: 1152 chunks (144 rows x 8)
                int row = c >> 3;
                int col = ((c & 7) ^ (row & 7)) * 8;
                async16(A + (size_t)(row0 + row) * DD + k0 + col, As + j * 512);
            } else {                           // B: 1536 chunks (192 rows x 8)
                int cb = c - 1152;
                int row = cb >> 3;
                int sec = row >> 6;
                int wrow = sec * DD + h * 64 + (row & 63);
                int col = ((cb & 7) ^ (row & 7)) * 8;
                async16(Wc + (size_t)wrow * DD + k0 + col, Bs + (j - 18) * 512);
            }
        }
        __syncthreads();

#pragma unroll
        for (int ks = 0; ks < 2; ks++) {
            int kch = ks * 4 + quad;
            bf16x8 bfv[3], afv[9];
#pragma unroll
            for (int ct = 0; ct < 3; ct++) {
                int rowb = wave * 48 + ct * 16 + l16;
                bfv[ct] = *(const bf16x8*)&Bs[rowb * 64 + ((kch ^ (rowb & 7)) * 8)];
            }
#pragma unroll
            for (int rt = 0; rt < 9; rt++) {
                int rowa = rt * 16 + l16;
                afv[rt] = *(const bf16x8*)&As[rowa * 64 + ((kch ^ (rowa & 7)) * 8)];
            }
#pragma unroll
            for (int rt = 0; rt < 9; rt++)
#pragma unroll
                for (int ct = 0; ct < 3; ct++)
                    acc[rt][ct] = __builtin_amdgcn_mfma_f32_16x16x32_bf16(afv[rt], bfv[ct], acc[rt][ct], 0, 0, 0);
        }
        __syncthreads();
    }

    // ---------------- epilogue phase 1: spill q,k (stride 72, padded) ----------------
    unsigned short* qL = pool;                 // [144][72]  (20736 B)
    unsigned short* kL = pool + 10368;         // [144][72]  (20736 B)
#pragma unroll
    for (int ct = 0; ct < 3; ct++) {
        int g = wave * 48 + ct * 16 + l16;     // wave-uniform section per ct
        int sec = g >> 6, e = g & 63;
        if (sec < 2) {
            unsigned short* dst = (sec == 0) ? qL : kL;
            float bias = (sec == 0) ? bq[h * 64 + e] : bk[h * 64 + e];
#pragma unroll
            for (int rt = 0; rt < 9; rt++)
#pragma unroll
                for (int r = 0; r < 4; r++) {
                    int row = rt * 16 + quad * 4 + r;
                    dst[row * 72 + e] = f2bf(acc[rt][ct][r] + bias);
                }
        }
    }
    __syncthreads();

    // ---------------- phase 2: QK^T per wave (batch = wave) ----------------
    const int bat = wave;
    const unsigned short* qB = qL + bat * 36 * 72;
    const unsigned short* kB = kL + bat * 36 * 72;
    int rq[3];
#pragma unroll
    for (int t = 0; t < 3; t++) { int rr = t * 16 + l16; rq[t] = rr < 36 ? rr : 35; }

    f32x4 aff[3][3] = {};
#pragma unroll
    for (int ks = 0; ks < 2; ks++) {
        bf16x8 afr[3], bfr[3];
#pragma unroll
        for (int t = 0; t < 3; t++) afr[t] = *(const bf16x8*)&qB[rq[t] * 72 + ks * 32 + quad * 8];
#pragma unroll
        for (int t = 0; t < 3; t++) bfr[t] = *(const bf16x8*)&kB[rq[t] * 72 + ks * 32 + quad * 8];
#pragma unroll
        for (int mt = 0; mt < 3; mt++)
#pragma unroll
            for (int nt = 0; nt < 3; nt++)
                aff[mt][nt] = __builtin_amdgcn_mfma_f32_16x16x32_bf16(afr[mt], bfr[nt], aff[mt][nt], 0, 0, 0);
    }

    // exs: per-lane direct loads (valid cells only)
    const float* exb = extra + ((size_t)((bg * 4 + bat) * 16 + h)) * 1296;
    float exv[3][4][3];
#pragma unroll
    for (int mt = 0; mt < 3; mt++)
#pragma unroll
        for (int r = 0; r < 4; r++) {
            int row = mt * 16 + quad * 4 + r;
#pragma unroll
            for (int nt = 0; nt < 3; nt++) {
                int col = nt * 16 + l16;
                exv[mt][r][nt] = (row < 36 && col < 36) ? exb[row * 36 + col] : 0.f;
            }
        }
    __syncthreads();   // q/k dead; pool becomes vwT | atts

    // ---------------- phase 3: softmax -> atts; spill vwT; zero pads ----------------
    unsigned short* vwT   = pool;                        // [4][64][72] bf16
    unsigned short* attsL = pool + 18432 + bat * 3456;   // per-batch [48][72] bf16
#pragma unroll
    for (int mt = 0; mt < 3; mt++) {
#pragma unroll
        for (int r = 0; r < 4; r++) {
            int row = mt * 16 + quad * 4 + r;
            float w[3];
#pragma unroll
            for (int nt = 0; nt < 3; nt++) {
                int col = nt * 16 + l16;
                bool valid = (row < 36) && (col < 36);
                w[nt] = valid ? (aff[mt][nt][r] * 0.125f + exv[mt][r][nt]) : -3.4e38f;
            }
            float mx = fmaxf(fmaxf(w[0], w[1]), w[2]);
#pragma unroll
            for (int d = 1; d < 16; d <<= 1) mx = fmaxf(mx, __shfl_xor(mx, d));
            float e0 = __expf(w[0] - mx), e1 = __expf(w[1] - mx), e2 = __expf(w[2] - mx);
            float s = e0 + e1 + e2;
#pragma unroll
            for (int d = 1; d < 16; d <<= 1) s += __shfl_xor(s, d);
            float rs = 1.0f / s;
            attsL[row * 72 + 0  + l16] = f2bf(e0 * rs);
            attsL[row * 72 + 16 + l16] = f2bf(e1 * rs);
            attsL[row * 72 + 32 + l16] = f2bf(e2 * rs);
        }
    }
    // zero atts cols 48..63 (K-pad for PV)
    for (int i = lane; i < 48 * 16; i += 64) attsL[(i >> 4) * 72 + 48 + (i & 15)] = 0;
    // spill vw section (waves holding sec==2 cols) into vwT[batch][e][m]
#pragma unroll
    for (int ct = 0; ct < 3; ct++) {
        int g = wave * 48 + ct * 16 + l16;
        int sec = g >> 6, e = g & 63;
        if (sec == 2) {
#pragma unroll
            for (int rt = 0; rt < 9; rt++)
#pragma unroll
                for (int r = 0; r < 4; r++) {
                    int row = rt * 16 + quad * 4 + r;   // 0..143
                    int bb = row / 36, m = row - bb * 36;
                    vwT[bb * 4608 + e * 72 + m] = f2bf(acc[rt][ct][r]);
                }
        }
    }
    // zero vwT m in [36,64) for own batch (K-pad)
    {
        unsigned short* vB = vwT + bat * 4608;
        for (int m = 36; m < 64; m++) vB[lane * 72 + m] = 0;
    }
    __syncthreads();

    // ---------------- phase 4: PV + store ----------------
    const unsigned short* vB = vwT + bat * 4608;
    f32x4 o[3][4] = {};
#pragma unroll
    for (int ks = 0; ks < 2; ks++) {
        bf16x8 pa[3], pb[4];
#pragma unroll
        for (int mt = 0; mt < 3; mt++) pa[mt] = *(const bf16x8*)&attsL[(mt * 16 + l16) * 72 + ks * 32 + quad * 8];
#pragma unroll
        for (int nt = 0; nt < 4; nt++) pb[nt] = *(const bf16x8*)&vB[(nt * 16 + l16) * 72 + ks * 32 + quad * 8];
#pragma unroll
        for (int mt = 0; mt < 3; mt++)
#pragma unroll
            for (int nt = 0; nt < 4; nt++)
                o[mt][nt] = __builtin_amdgcn_mfma_f32_16x16x32_bf16(pa[mt], pb[nt], o[mt][nt], 0, 0, 0);
    }

    float bo[4];
#pragma unroll
    for (int nt = 0; nt < 4; nt++) bo[nt] = bout[h * 64 + nt * 16 + l16];
    const size_t obase = (size_t)((bg * 4 + bat) * 36) * DD + h * 64;
#pragma unroll
    for (int mt = 0; mt < 3; mt++)
#pragma unroll
        for (int r = 0; r < 4; r++) {
            int n = mt * 16 + quad * 4 + r;
            if (n < 36) {
#pragma unroll
                for (int nt = 0; nt < 4; nt++)
                    out[obase + (size_t)n * DD + nt * 16 + l16] = o[mt][nt][r] + bo[nt];
            }
        }
}

// ---------------- launcher ----------------
extern "C" void kernel_launch(void* const* d_in, const int* in_sizes, int n_in,
                              void* d_out, int out_size, void* d_ws, size_t ws_size,
                              hipStream_t stream) {
    const float* roi  = (const float*)d_in[0];
    const int*   adj  = (const int*)  d_in[1];
    const float* pe   = (const float*)d_in[2];
    const float* lbl  = (const float*)d_in[3];
    const float* Wq   = (const float*)d_in[4];
    const float* bq   = (const float*)d_in[5];
    const float* Wk   = (const float*)d_in[6];
    const float* bk   = (const float*)d_in[7];
    const float* Wpos = (const float*)d_in[8];
    const float* bpos = (const float*)d_in[9];
    const float* Wout = (const float*)d_in[10];
    const float* bout = (const float*)d_in[11];
    float* out = (float*)d_out;

    char* w = (char*)d_ws;
    unsigned short* roi_bf  = (unsigned short*)(w);               // 9.4 MB
    unsigned short* Wcat_bf = (unsigned short*)(w + 9437184);     // 6.3 MB
    float*          extra   = (float*)(w + 15728640);             // 10.6 MB

    prep_kernel<<<8328, 256, 0, stream>>>(roi, Wq, Wk, Wout, pe, Wpos, bpos, adj, lbl,
                                          roi_bf, Wcat_bf, extra);
    fused_kernel<<<32 * 16, 256, 0, stream>>>(roi_bf, Wcat_bf, bq, bk, extra, bout, out);
}

// Round 7
// 170.607 us; speedup vs baseline: 1.4978x; 1.0428x over previous
//
#include <hip/hip_runtime.h>
#include <hip/hip_bf16.h>

#define BB 128
#define NN 36
#define DD 1024
#define HH 16
#define ROWS (BB*NN)          // 4608

typedef __attribute__((ext_vector_type(8))) __bf16 bf16x8;
typedef __attribute__((ext_vector_type(4))) float f32x4;
typedef __attribute__((ext_vector_type(4))) unsigned short us4;

__device__ inline unsigned short f2bf(float f) {
    __hip_bfloat16 h = __float2bfloat16(f);
    return *reinterpret_cast<unsigned short*>(&h);
}

__device__ inline void async16(const unsigned short* g, unsigned short* l) {
    __builtin_amdgcn_global_load_lds((const __attribute__((address_space(1))) unsigned int*)g,
                                     (__attribute__((address_space(3))) unsigned int*)l, 16, 0, 0);
}

// ---------------- prep: roi->bf16, W->bf16, extra  (one launch) ----------------
// grid: [0,4608) roi cvt | [4608,7680) weight cvt | [7680,8328) extra
__global__ __launch_bounds__(256) void prep_kernel(const float* __restrict__ roi,
                                                   const float* __restrict__ Wq,
                                                   const float* __restrict__ Wk,
                                                   const float* __restrict__ Wout,
                                                   const float* __restrict__ pe,
                                                   const float* __restrict__ Wpos,
                                                   const float* __restrict__ bpos,
                                                   const int* __restrict__ adj,
                                                   const float* __restrict__ lbl,
                                                   unsigned short* __restrict__ roi_bf,
                                                   unsigned short* __restrict__ Wcat_bf,
                                                   float* __restrict__ extra) {
    const int bid = blockIdx.x, tid = threadIdx.x;
    if (bid < 4608) {
        int i = bid * 256 + tid;
        f32x4 v = ((const f32x4*)roi)[i];
        us4 o;
        o.x = f2bf(v[0]); o.y = f2bf(v[1]); o.z = f2bf(v[2]); o.w = f2bf(v[3]);
        ((us4*)roi_bf)[i] = o;
        return;
    }
    if (bid < 7680) {
        int wb = bid - 4608;
        int sel = wb >> 10;
        const float* src = sel == 0 ? Wq : (sel == 1 ? Wk : Wout);
        int i = (wb & 1023) * 256 + tid;
        f32x4 v = ((const f32x4*)src)[i];
        us4 o;
        o.x = f2bf(v[0]); o.y = f2bf(v[1]); o.z = f2bf(v[2]); o.w = f2bf(v[3]);
        ((us4*)(Wcat_bf + (size_t)sel * DD * DD))[i] = o;
        return;
    }
    __shared__ __align__(16) float wps[HH * 64];
    __shared__ float bps[HH];
    for (int i = tid; i < HH * 64; i += 256) wps[i] = Wpos[i];
    if (tid < HH) bps[tid] = bpos[tid];
    __syncthreads();

    int idx = (bid - 7680) * 256 + tid;           // one (b,n,m); 165888 total
    f32x4 pr[16];
    const f32x4* pv = (const f32x4*)(pe + (size_t)idx * 64);
#pragma unroll
    for (int j = 0; j < 16; j++) pr[j] = pv[j];
    int a = adj[idx];
    float add = lbl[idx] + (a > 0 ? 0.f : -9e15f);
    int b = idx / 1296, nm = idx % 1296;
    size_t obase = (size_t)b * (16 * 1296) + nm;
    for (int hh = 0; hh < 16; hh++) {
        const f32x4* wv = (const f32x4*)(wps + hh * 64);
        f32x4 acc4 = {0.f, 0.f, 0.f, 0.f};
#pragma unroll
        for (int j = 0; j < 16; j++) acc4 += pr[j] * wv[j];
        float d = acc4[0] + acc4[1] + acc4[2] + acc4[3] + bps[hh];
        d = fmaxf(d, 0.f);
        d = __logf(fmaxf(d, 1e-6f));
        extra[obase + (size_t)hh * 1296] = d + add;
    }
}

// ---------------- fused GEMM + attention: one block per (4-batch group, head) ----------------
// GEMM tile: M=144 (4 batches x 36), N=192 ([q|k|vw] head slices), K=1024.
// K-loop fully unrolled: per-slot base pointers hoisted, k-offset folds into the
// global_load_lds 13-bit instruction offset (max 1920 B) -> zero per-iter addr VALU.
__global__ __launch_bounds__(256, 2) void fused_kernel(const unsigned short* __restrict__ A,
                                                       const unsigned short* __restrict__ Wc,
                                                       const float* __restrict__ bq,
                                                       const float* __restrict__ bk,
                                                       const float* __restrict__ extra,
                                                       const float* __restrict__ bout,
                                                       float* __restrict__ out) {
    __shared__ __align__(16) unsigned short pool[29184];   // 58368 B
    const int tid  = threadIdx.x;
    const int wave = tid >> 6, lane = tid & 63;
    const int quad = lane >> 4, l16 = lane & 15;
    const int h  = blockIdx.x & 15;
    const int bg = blockIdx.x >> 4;            // 0..31, 4 batches each
    const int row0 = bg * 144;

    unsigned short* As = pool;                 // [144][64] bf16, XOR-swizzled (18 slots x 512)
    unsigned short* Bs = pool + 9216;          // [192][64] bf16, XOR-swizzled (24 slots x 512)

    // hoisted staging addresses: slot j = wave + 4*i, i = 0..10 (j<42 valid)
    const unsigned short* gsrc[11];
    unsigned short* ldst[11];
#pragma unroll
    for (int i = 0; i < 11; i++) {
        int j = wave + 4 * i;
        int c = j * 64 + lane;
        if (j < 18) {                          // A: 1152 chunks (144 rows x 8)
            int row = c >> 3;
            int col = ((c & 7) ^ (row & 7)) * 8;
            gsrc[i] = A + (size_t)(row0 + row) * DD + col;
            ldst[i] = As + j * 512;
        } else {                               // B: 1536 chunks (192 rows x 8)
            int cb = c - 1152;
            int row = cb >> 3;
            int sec = row >> 6;
            int wrow = sec * DD + h * 64 + (row & 63);
            int col = ((cb & 7) ^ (row & 7)) * 8;
            gsrc[i] = Wc + (size_t)wrow * DD + col;
            ldst[i] = Bs + (j - 18) * 512;
        }
    }

    f32x4 acc[9][3] = {};                      // rows rt*16, wave's 48-col slice ct*16

#pragma unroll
    for (int k0i = 0; k0i < 16; k0i++) {
#pragma unroll
        for (int i = 0; i < 11; i++) {
            if (i < 10 || wave < 2)
                async16(gsrc[i] + k0i * 64, ldst[i]);
        }
        __syncthreads();

#pragma unroll
        for (int ks = 0; ks < 2; ks++) {
            int kch = ks * 4 + quad;
            bf16x8 bfv[3], afv[9];
#pragma unroll
            for (int ct = 0; ct < 3; ct++) {
                int rowb = wave * 48 + ct * 16 + l16;
                bfv[ct] = *(const bf16x8*)&Bs[rowb * 64 + ((kch ^ (rowb & 7)) * 8)];
            }
#pragma unroll
            for (int rt = 0; rt < 9; rt++) {
                int rowa = rt * 16 + l16;
                afv[rt] = *(const bf16x8*)&As[rowa * 64 + ((kch ^ (rowa & 7)) * 8)];
            }
#pragma unroll
            for (int rt = 0; rt < 9; rt++)
#pragma unroll
                for (int ct = 0; ct < 3; ct++)
                    acc[rt][ct] = __builtin_amdgcn_mfma_f32_16x16x32_bf16(afv[rt], bfv[ct], acc[rt][ct], 0, 0, 0);
        }
        __syncthreads();
    }

    // ---------------- prefetch extra + bout (hidden under spill + QK) ----------------
    const int bat = wave;
    const float* exb = extra + ((size_t)((bg * 4 + bat) * 16 + h)) * 1296;
    float exv[3][4][3];
#pragma unroll
    for (int mt = 0; mt < 3; mt++)
#pragma unroll
        for (int r = 0; r < 4; r++) {
            int row = mt * 16 + quad * 4 + r;
#pragma unroll
            for (int nt = 0; nt < 3; nt++) {
                int col = nt * 16 + l16;
                exv[mt][r][nt] = (row < 36 && col < 36) ? exb[row * 36 + col] : 0.f;
            }
        }
    float bo[4];
#pragma unroll
    for (int nt = 0; nt < 4; nt++) bo[nt] = bout[h * 64 + nt * 16 + l16];

    // ---------------- phase 1: spill q,k (stride 72) ----------------
    unsigned short* qL = pool;                 // [144][72]
    unsigned short* kL = pool + 10368;         // [144][72]
#pragma unroll
    for (int ct = 0; ct < 3; ct++) {
        int g = wave * 48 + ct * 16 + l16;
        int sec = g >> 6, e = g & 63;
        if (sec < 2) {
            unsigned short* dst = (sec == 0) ? qL : kL;
            float bias = (sec == 0) ? bq[h * 64 + e] : bk[h * 64 + e];
#pragma unroll
            for (int rt = 0; rt < 9; rt++)
#pragma unroll
                for (int r = 0; r < 4; r++) {
                    int row = rt * 16 + quad * 4 + r;
                    dst[row * 72 + e] = f2bf(acc[rt][ct][r] + bias);
                }
        }
    }
    __syncthreads();

    // ---------------- phase 2: QK^T per wave (batch = wave) ----------------
    const unsigned short* qB = qL + bat * 36 * 72;
    const unsigned short* kB = kL + bat * 36 * 72;
    int rq[3];
#pragma unroll
    for (int t = 0; t < 3; t++) { int rr = t * 16 + l16; rq[t] = rr < 36 ? rr : 35; }

    f32x4 aff[3][3] = {};
#pragma unroll
    for (int ks = 0; ks < 2; ks++) {
        bf16x8 afr[3], bfr[3];
#pragma unroll
        for (int t = 0; t < 3; t++) afr[t] = *(const bf16x8*)&qB[rq[t] * 72 + ks * 32 + quad * 8];
#pragma unroll
        for (int t = 0; t < 3; t++) bfr[t] = *(const bf16x8*)&kB[rq[t] * 72 + ks * 32 + quad * 8];
#pragma unroll
        for (int mt = 0; mt < 3; mt++)
#pragma unroll
            for (int nt = 0; nt < 3; nt++)
                aff[mt][nt] = __builtin_amdgcn_mfma_f32_16x16x32_bf16(afr[mt], bfr[nt], aff[mt][nt], 0, 0, 0);
    }
    __syncthreads();   // q/k dead; pool becomes vwT | atts

    // ---------------- phase 3: softmax -> atts (stride 56); spill vwT ----------------
    // atts stride 56 shorts = 112 B: softmax writes cols 0..47 (fits), rows alias 2-way
    // on b128 reads (free). Cols 36..47 are exact zeros (masked lanes write exp(-inf)=0).
    unsigned short* vwT   = pool;                        // [4][64][72] bf16 (18432)
    unsigned short* attsL = pool + 18432 + bat * 2688;   // per-batch [48][56] bf16
#pragma unroll
    for (int mt = 0; mt < 3; mt++) {
#pragma unroll
        for (int r = 0; r < 4; r++) {
            int row = mt * 16 + quad * 4 + r;
            float w[3];
#pragma unroll
            for (int nt = 0; nt < 3; nt++) {
                int col = nt * 16 + l16;
                bool valid = (row < 36) && (col < 36);
                w[nt] = valid ? (aff[mt][nt][r] * 0.125f + exv[mt][r][nt]) : -3.4e38f;
            }
            float mx = fmaxf(fmaxf(w[0], w[1]), w[2]);
#pragma unroll
            for (int d = 1; d < 16; d <<= 1) mx = fmaxf(mx, __shfl_xor(mx, d));
            float e0 = __expf(w[0] - mx), e1 = __expf(w[1] - mx), e2 = __expf(w[2] - mx);
            float s = e0 + e1 + e2;
#pragma unroll
            for (int d = 1; d < 16; d <<= 1) s += __shfl_xor(s, d);
            float rs = 1.0f / s;
            attsL[row * 56 + 0  + l16] = f2bf(e0 * rs);
            attsL[row * 56 + 16 + l16] = f2bf(e1 * rs);
            attsL[row * 56 + 32 + l16] = f2bf(e2 * rs);
        }
    }
    // spill vw section into vwT[batch][e][m]
#pragma unroll
    for (int ct = 0; ct < 3; ct++) {
        int g = wave * 48 + ct * 16 + l16;
        int sec = g >> 6, e = g & 63;
        if (sec == 2) {
#pragma unroll
            for (int rt = 0; rt < 9; rt++)
#pragma unroll
                for (int r = 0; r < 4; r++) {
                    int row = rt * 16 + quad * 4 + r;   // 0..143
                    int bb = row / 36, m = row - bb * 36;
                    vwT[bb * 4608 + e * 72 + m] = f2bf(acc[rt][ct][r]);
                }
        }
    }
    {   // zero vwT m in [36,64) for own batch (K-pad for PV ks=1)
        unsigned short* vB = vwT + bat * 4608;
        for (int m = 36; m < 64; m++) vB[lane * 72 + m] = 0;
    }
    __syncthreads();

    // ---------------- phase 4: PV + store ----------------
    // PV K=64 (m padded): ks=0 reads atts cols 0..31; ks=1 needs cols 32..63 but only
    // 32..35 are nonzero -> quads 0,1 read cols 32..47 (36..47 zeros), quads 2,3 zero-frag.
    const unsigned short* vB = vwT + bat * 4608;
    f32x4 o[3][4] = {};
    {
        bf16x8 pa[3], pb[4];
        // ks = 0: cols 0..31
#pragma unroll
        for (int mt = 0; mt < 3; mt++) pa[mt] = *(const bf16x8*)&attsL[(mt * 16 + l16) * 56 + quad * 8];
#pragma unroll
        for (int nt = 0; nt < 4; nt++) pb[nt] = *(const bf16x8*)&vB[(nt * 16 + l16) * 72 + quad * 8];
#pragma unroll
        for (int mt = 0; mt < 3; mt++)
#pragma unroll
            for (int nt = 0; nt < 4; nt++)
                o[mt][nt] = __builtin_amdgcn_mfma_f32_16x16x32_bf16(pa[mt], pb[nt], o[mt][nt], 0, 0, 0);
        // ks = 1: cols 32..63
        bf16x8 zf = {};
#pragma unroll
        for (int mt = 0; mt < 3; mt++)
            pa[mt] = (quad < 2) ? *(const bf16x8*)&attsL[(mt * 16 + l16) * 56 + 32 + quad * 8] : zf;
#pragma unroll
        for (int nt = 0; nt < 4; nt++) pb[nt] = *(const bf16x8*)&vB[(nt * 16 + l16) * 72 + 32 + quad * 8];
#pragma unroll
        for (int mt = 0; mt < 3; mt++)
#pragma unroll
            for (int nt = 0; nt < 4; nt++)
                o[mt][nt] = __builtin_amdgcn_mfma_f32_16x16x32_bf16(pa[mt], pb[nt], o[mt][nt], 0, 0, 0);
    }

    const size_t obase = (size_t)((bg * 4 + bat) * 36) * DD + h * 64;
#pragma unroll
    for (int mt = 0; mt < 3; mt++)
#pragma unroll
        for (int r = 0; r < 4; r++) {
            int n = mt * 16 + quad * 4 + r;
            if (n < 36) {
#pragma unroll
                for (int nt = 0; nt < 4; nt++)
                    out[obase + (size_t)n * DD + nt * 16 + l16] = o[mt][nt][r] + bo[nt];
            }
        }
}

// ---------------- launcher ----------------
extern "C" void kernel_launch(void* const* d_in, const int* in_sizes, int n_in,
                              void* d_out, int out_size, void* d_ws, size_t ws_size,
                              hipStream_t stream) {
    const float* roi  = (const float*)d_in[0];
    const int*   adj  = (const int*)  d_in[1];
    const float* pe   = (const float*)d_in[2];
    const float* lbl  = (const float*)d_in[3];
    const float* Wq   = (const float*)d_in[4];
    const float* bq   = (const float*)d_in[5];
    const float* Wk   = (const float*)d_in[6];
    const float* bk   = (const float*)d_in[7];
    const float* Wpos = (const float*)d_in[8];
    const float* bpos = (const float*)d_in[9];
    const float* Wout = (const float*)d_in[10];
    const float* bout = (const float*)d_in[11];
    float* out = (float*)d_out;

    char* w = (char*)d_ws;
    unsigned short* roi_bf  = (unsigned short*)(w);               // 9.4 MB
    unsigned short* Wcat_bf = (unsigned short*)(w + 9437184);     // 6.3 MB
    float*          extra   = (float*)(w + 15728640);             // 10.6 MB

    prep_kernel<<<8328, 256, 0, stream>>>(roi, Wq, Wk, Wout, pe, Wpos, bpos, adj, lbl,
                                          roi_bf, Wcat_bf, extra);
    fused_kernel<<<32 * 16, 256, 0, stream>>>(roi_bf, Wcat_bf, bq, bk, extra, bout, out);
}